// Round 8
// baseline (363.456 us; speedup 1.0000x reference)
//
#include <hip/hip_runtime.h>
#include <hip/hip_bf16.h>

#define NN 25000
#define RR 16
#define H0 256
#define H1 256
#define NBASE 16
#define EE 800000
#define NKEY (NN*RR)        // 400,000 segments, key = s*RR + p
#define NKEY_PAD 400384     // 391*1024
#define SCAN_NB 391

#define BM 16               // output rows per block -> 1563 blocks (6.1/CU)
#define CAPE 1024           // LDS edge-cache per block (avg span 512, Poisson)

// workspace layout (bytes), total ~10.1 MB (cur region retained but unused):
static const size_t CNT_OFF  = 0;          // int[NKEY_PAD]   1,601,536
static const size_t CUR_OFF  = 1601536;    // (unused)
static const size_t OFFS_OFF = 3203072;    // int[NKEY_PAD]   1,601,536
static const size_t PART_OFF = 4804608;    // int[512]        2,048
static const size_t PERM_OFF = 4806656;    // int[EE]         3,200,000
static const size_t W2_OFF   = 8006656;    // bf16 MFMA-frag-packed W: 2,097,152

typedef short bf16x8 __attribute__((ext_vector_type(8)));
typedef float f32x4  __attribute__((ext_vector_type(4)));

static __device__ __forceinline__ unsigned short f2bf(float f) {
    union { float f; unsigned u; } v; v.f = f;
    unsigned x = v.u;
    return (unsigned short)((x + 0x7FFFu + ((x >> 16) & 1u)) >> 16);  // RNE
}

// ---------------------------------------------------------------------------
// W[r][i][j] = sum_b comps[r][b]*bases[b][i][j], packed straight into the
// 16x16x32 MFMA B-fragment lane order as bf16:
//   B-frag reg u of lane l for (r, ks, nb) = W[r][ks*32+(l>>4)*8+u][nb*16+(l&15)]
__global__ __launch_bounds__(256) void k_weights(const float* __restrict__ comps,
                                                 const float* __restrict__ bases,
                                                 unsigned short* __restrict__ W2) {
    __shared__ float sc[RR * NBASE];
    int t = threadIdx.x;
    sc[t] = comps[t];
    __syncthreads();
    int i = blockIdx.x;            // 0..255 (k dim)
    int j = t;                     // 0..255 (n dim)
    int ij = i * 256 + j;
    float bv[NBASE];
#pragma unroll
    for (int b = 0; b < NBASE; ++b) bv[b] = bases[b * H0 * H1 + ij];
    int ks = i >> 5, u = i & 7, lq = (i >> 3) & 3;
    int nb = j >> 4, ln = j & 15;
#pragma unroll
    for (int r = 0; r < RR; ++r) {
        float acc = 0.f;
#pragma unroll
        for (int b = 0; b < NBASE; ++b) acc = fmaf(sc[r * NBASE + b], bv[b], acc);
        size_t sidx = (((size_t)(r * 8 + ks) * 16 + nb) * 64 + lq * 16 + ln) * 8 + u;
        W2[sidx] = f2bf(acc);
    }
}

// ---------------------------------------------------------------------------
__global__ __launch_bounds__(256) void k_cnt(const int* __restrict__ triples,
                                             int* __restrict__ cnt) {
    int e = blockIdx.x * 256 + threadIdx.x;
    if (e >= EE) return;
    int s = triples[3 * e];
    int p = triples[3 * e + 1];
    atomicAdd(&cnt[s * RR + p], 1);
}

__global__ __launch_bounds__(256) void k_scan1(const int* __restrict__ cnt,
                                               int* __restrict__ part) {
    __shared__ int sh[256];
    int t = threadIdx.x;
    int4 v = *(const int4*)(cnt + blockIdx.x * 1024 + t * 4);
    sh[t] = v.x + v.y + v.z + v.w;
    __syncthreads();
    for (int off = 128; off > 0; off >>= 1) {
        if (t < off) sh[t] += sh[t + off];
        __syncthreads();
    }
    if (t == 0) part[blockIdx.x] = sh[0];
}

__global__ void k_scan2(int* __restrict__ part) {
    __shared__ int sh[512];
    int t = threadIdx.x;
    sh[t] = (t < SCAN_NB) ? part[t] : 0;
    __syncthreads();
    for (int off = 1; off < 512; off <<= 1) {
        int v = (t >= off) ? sh[t - off] : 0;
        __syncthreads();
        sh[t] += v;
        __syncthreads();
    }
    if (t < SCAN_NB) part[t] = (t ? sh[t - 1] : 0);
}

__global__ __launch_bounds__(256) void k_scan3(const int* __restrict__ cnt,
                                               const int* __restrict__ part,
                                               int* __restrict__ offs) {
    __shared__ int sh[256];
    int t = threadIdx.x;
    int base = blockIdx.x * 1024 + t * 4;
    int4 v = *(const int4*)(cnt + base);
    sh[t] = v.x + v.y + v.z + v.w;
    __syncthreads();
    for (int off = 1; off < 256; off <<= 1) {
        int x = (t >= off) ? sh[t - off] : 0;
        __syncthreads();
        sh[t] += x;
        __syncthreads();
    }
    int texcl = part[blockIdx.x] + (t ? sh[t - 1] : 0);
    int4 w;
    w.x = texcl;
    w.y = texcl + v.x;
    w.z = texcl + v.x + v.y;
    w.w = texcl + v.x + v.y + v.z;
    *(int4*)(offs + base) = w;
}

// rank via atomicSub on cnt (no separate cursor array); cnt is dead after this
__global__ __launch_bounds__(256) void k_fill(const int* __restrict__ triples,
                                              const int* __restrict__ offs,
                                              int* __restrict__ cnt,
                                              int* __restrict__ perm_o) {
    int e = blockIdx.x * 256 + threadIdx.x;
    if (e >= EE) return;
    int s = triples[3 * e];
    int p = triples[3 * e + 1];
    int o = triples[3 * e + 2];
    int key = s * RR + p;
    int r = atomicSub(&cnt[key], 1) - 1;      // rank in [0, c)
    perm_o[offs[key] + r] = o;
}

// ---------------------------------------------------------------------------
// Fused: block owns BM=16 output rows; double-buffered As pipeline:
//   agg(p+1) -> buf[1-b] issued BEFORE MFMA(p, buf[b]); 1 barrier / iter.
__global__ __launch_bounds__(256, 6) void k_fused(const float* __restrict__ nodes,
                                                  const unsigned short* __restrict__ W2,
                                                  const int* __restrict__ offs,
                                                  const int* __restrict__ perm_o,
                                                  const float* __restrict__ bias,
                                                  float* __restrict__ out) {
    __shared__ int offs_l[BM * RR + 1];          // 257 ints
    __shared__ int eo[CAPE];                     // 4 KB
    __shared__ unsigned short As[2][BM][264];    // 2 x 8.25 KB (+8 pad/row)

    int t = threadIdx.x;
    int l = t & 63;                // lane
    int w = t >> 6;                // wave 0..3
    int m0 = blockIdx.x * BM;
    int key0 = m0 * RR;

    for (int idx = t; idx < BM * RR + 1; idx += 256) {
        int g = key0 + idx;
        if (g > NKEY_PAD - 1) g = NKEY_PAD - 1;   // padded region scans to EE
        offs_l[idx] = offs[g];
    }
    __syncthreads();
    int base0 = offs_l[0];
    int span  = offs_l[BM * RR] - base0;
    for (int j = t; j < span && j < CAPE; j += 256) eo[j] = perm_o[base0 + j];

    f32x4 acc[4];
#pragma unroll
    for (int ni = 0; ni < 4; ++ni) acc[ni] = (f32x4){0.f, 0.f, 0.f, 0.f};

    // wave w aggregates rows w*4 .. w*4+3 of relation p into As[buf]
    auto aggregate = [&](int p, int buf) {
#pragma unroll
        for (int i = 0; i < 4; ++i) {
            int m = w * 4 + i;
            int s = m0 + m;
            float sx = 0.f, sy = 0.f, sz = 0.f, sw = 0.f;
            int c = 0;
            if (s < NN) {
                int loc = m * RR + p;
                int b = offs_l[loc] - base0;
                c = offs_l[loc + 1] - offs_l[loc];
                int j2 = 0;
                for (; j2 + 1 < c; j2 += 2) {
                    int x1 = b + j2, x2 = b + j2 + 1;
                    int o1 = (x1 < CAPE) ? eo[x1] : perm_o[base0 + x1];
                    int o2 = (x2 < CAPE) ? eo[x2] : perm_o[base0 + x2];
                    float4 v1 = *(const float4*)(nodes + (size_t)o1 * H0 + l * 4);
                    float4 v2 = *(const float4*)(nodes + (size_t)o2 * H0 + l * 4);
                    sx += v1.x + v2.x; sy += v1.y + v2.y;
                    sz += v1.z + v2.z; sw += v1.w + v2.w;
                }
                if (j2 < c) {
                    int x1 = b + j2;
                    int o1 = (x1 < CAPE) ? eo[x1] : perm_o[base0 + x1];
                    float4 v1 = *(const float4*)(nodes + (size_t)o1 * H0 + l * 4);
                    sx += v1.x; sy += v1.y; sz += v1.z; sw += v1.w;
                }
            }
            float inv = c ? 1.f / (float)c : 0.f;
            ushort4 pk;
            pk.x = f2bf(sx * inv); pk.y = f2bf(sy * inv);
            pk.z = f2bf(sz * inv); pk.w = f2bf(sw * inv);
            *(ushort4*)&As[buf][m][l * 4] = pk;
        }
    };

    __syncthreads();               // eo preload complete
    aggregate(0, 0);
    __syncthreads();               // As[0] ready

    for (int p = 0; p < RR; ++p) {
        if (p + 1 < RR) aggregate(p + 1, (p + 1) & 1);   // gathers overlap MFMA
        int cb = p & 1;
        const unsigned short* Wp = W2 + (size_t)p * 65536;
#pragma unroll
        for (int ks = 0; ks < 8; ++ks) {
            bf16x8 a0 = *(const bf16x8*)&As[cb][(l & 15)][ks * 32 + (l >> 4) * 8];
            const unsigned short* wb = Wp + ((size_t)ks * 16 + w * 4) * 512 + (size_t)l * 8;
            bf16x8 b0 = *(const bf16x8*)(wb);
            bf16x8 b1 = *(const bf16x8*)(wb + 512);
            bf16x8 b2 = *(const bf16x8*)(wb + 1024);
            bf16x8 b3 = *(const bf16x8*)(wb + 1536);
            acc[0] = __builtin_amdgcn_mfma_f32_16x16x32_bf16(a0, b0, acc[0], 0, 0, 0);
            acc[1] = __builtin_amdgcn_mfma_f32_16x16x32_bf16(a0, b1, acc[1], 0, 0, 0);
            acc[2] = __builtin_amdgcn_mfma_f32_16x16x32_bf16(a0, b2, acc[2], 0, 0, 0);
            acc[3] = __builtin_amdgcn_mfma_f32_16x16x32_bf16(a0, b3, acc[3], 0, 0, 0);
        }
        __syncthreads();           // As[1-cb] writes done; As[cb] reads done
    }

    // ---- epilogue: C/D layout col=lane&15, row=(lane>>4)*4+reg
    int colbase = w * 64 + (l & 15);
    float bl[4];
#pragma unroll
    for (int ni = 0; ni < 4; ++ni) bl[ni] = bias[colbase + ni * 16];
#pragma unroll
    for (int j = 0; j < 4; ++j) {
        int row = m0 + (l >> 4) * 4 + j;
        if (row < NN) {
#pragma unroll
            for (int ni = 0; ni < 4; ++ni)
                out[(size_t)row * H1 + colbase + ni * 16] = acc[ni][j] + bl[ni];
        }
    }
}

// ---------------------------------------------------------------------------
extern "C" void kernel_launch(void* const* d_in, const int* in_sizes, int n_in,
                              void* d_out, int out_size, void* d_ws, size_t ws_size,
                              hipStream_t stream) {
    const int*   triples = (const int*)d_in[0];
    const float* nodes   = (const float*)d_in[1];
    const float* comps   = (const float*)d_in[2];
    const float* bases   = (const float*)d_in[3];
    const float* bias    = (const float*)d_in[4];
    float* out = (float*)d_out;

    char* ws = (char*)d_ws;
    int*            cnt    = (int*)(ws + CNT_OFF);
    int*            offs   = (int*)(ws + OFFS_OFF);
    int*            part   = (int*)(ws + PART_OFF);
    int*            perm_o = (int*)(ws + PERM_OFF);
    unsigned short* W2     = (unsigned short*)(ws + W2_OFF);

    hipMemsetAsync(ws + CNT_OFF, 0, 1601536, stream);  // cnt only

    k_weights<<<256, 256, 0, stream>>>(comps, bases, W2);
    k_cnt<<<(EE + 255) / 256, 256, 0, stream>>>(triples, cnt);
    k_scan1<<<SCAN_NB, 256, 0, stream>>>(cnt, part);
    k_scan2<<<1, 512, 0, stream>>>(part);
    k_scan3<<<SCAN_NB, 256, 0, stream>>>(cnt, part, offs);
    k_fill<<<(EE + 255) / 256, 256, 0, stream>>>(triples, offs, cnt, perm_o);
    k_fused<<<(NN + BM - 1) / BM, 256, 0, stream>>>(nodes, W2, offs, perm_o, bias, out);
}